// Round 1
// baseline (597.756 us; speedup 1.0000x reference)
//
#include <hip/hip_runtime.h>
#include <hip/hip_bf16.h>

#define B_  32
#define R_  256
#define T_  512
#define C_  16
#define C1_ 64
#define C2_ 128

typedef short short8 __attribute__((ext_vector_type(8)));   // 8 bf16 = 4 VGPRs (MFMA A/B frag)
typedef float f32x4  __attribute__((ext_vector_type(4)));   // MFMA C/D frag

// ---------- bf16 helpers (RNE rounding) ----------
__device__ __forceinline__ unsigned short f2bf(float f) {
    unsigned u = __float_as_uint(f);
    return (unsigned short)((u + 0x7fffu + ((u >> 16) & 1u)) >> 16);
}

// =====================================================================
// K0: W_edge fp32 [o][c][r] -> Wb bf16 (same flat order), one-time cvt.
// =====================================================================
__global__ __launch_bounds__(256) void k0_wcvt(const float* __restrict__ W,
                                               unsigned short* __restrict__ Wb) {
    const int i = (blockIdx.x * 256 + threadIdx.x) * 4;   // 262144 total
    float4 v = *(const float4*)(W + i);
    uint2 pk;
    pk.x = (unsigned)f2bf(v.x) | ((unsigned)f2bf(v.y) << 16);
    pk.y = (unsigned)f2bf(v.z) | ((unsigned)f2bf(v.w) << 16);
    *(uint2*)(Wb + i) = pk;
}

// =====================================================================
// K1: x[B,R,T,C] fp32 -> y[B,C,R,T] bf16, rows centered & L2-normalized.
// =====================================================================
__global__ __launch_bounds__(256) void k1_normalize(const float* __restrict__ x,
                                                    unsigned short* __restrict__ y) {
    const int r = blockIdx.x, b = blockIdx.y, tid = threadIdx.x;
    __shared__ float xs[T_ * C_];          // 32 KB
    __shared__ float psum[16][17], psq[16][17];
    __shared__ float s_mean[16], s_inv[16];

    const float4* src = reinterpret_cast<const float4*>(x + ((size_t)(b * R_ + r)) * T_ * C_);
    float4* dst = reinterpret_cast<float4*>(xs);
#pragma unroll
    for (int j = 0; j < 8; ++j) dst[tid + j * 256] = src[tid + j * 256];
    __syncthreads();

    {
        const int c = tid & 15, seg = tid >> 4;
        float s = 0.f, q = 0.f;
#pragma unroll
        for (int i = 0; i < 32; ++i) {
            float v = xs[(seg * 32 + i) * C_ + c];
            s += v; q += v * v;
        }
        psum[seg][c] = s; psq[seg][c] = q;
    }
    __syncthreads();
    if (tid < 16) {
        float S = 0.f, Q = 0.f;
#pragma unroll
        for (int g = 0; g < 16; ++g) { S += psum[g][tid]; Q += psq[g][tid]; }
        float mean = S * (1.f / T_);
        float nrm2 = Q - S * mean;
        s_mean[tid] = mean;
        s_inv[tid] = rsqrtf(nrm2);
    }
    __syncthreads();

    const int cc = tid >> 4, l = tid & 15;
    const float mean = s_mean[cc], inv = s_inv[cc];
    unsigned* out = reinterpret_cast<unsigned*>(y + (((size_t)(b * C_ + cc)) * R_ + r) * T_);
#pragma unroll
    for (int j = 0; j < 16; ++j) {
        const int t = j * 32 + l * 2;
        float v0 = (xs[t * C_ + cc] - mean) * inv;
        float v1 = (xs[(t + 1) * C_ + cc] - mean) * inv;
        out[t >> 1] = (unsigned)f2bf(v0) | ((unsigned)f2bf(v1) << 16);
    }
}

// =====================================================================
// K1t: y[b,c,r,t] -> yT[b,c,t,r]  (bf16 transpose, register repack,
// no LDS). Thread: 8 rows x 4 t per iter; emits 4 t-rows x 8-r uint4.
// =====================================================================
__global__ __launch_bounds__(256) void k1t_transpose(const unsigned short* __restrict__ y,
                                                     unsigned short* __restrict__ yT) {
    const int c = blockIdx.x, b = blockIdx.y;
    const unsigned short* src = y + ((size_t)(b * C_ + c)) * R_ * T_;
    unsigned short* dstp = yT + ((size_t)(b * C_ + c)) * T_ * R_;
    const int tg = threadIdx.x & 7;          // t-group
    const int r0 = (threadIdx.x >> 3) * 8;   // 8-row strip
#pragma unroll 4
    for (int it = 0; it < 16; ++it) {
        const int t0 = (tg + 8 * it) * 4;
        uint2 u[8];
#pragma unroll
        for (int k = 0; k < 8; ++k)
            u[k] = *(const uint2*)(src + (size_t)(r0 + k) * T_ + t0);
#pragma unroll
        for (int j = 0; j < 4; ++j) {
            unsigned e[8];
#pragma unroll
            for (int k = 0; k < 8; ++k) {
                unsigned comp = (j < 2) ? u[k].x : u[k].y;
                e[k] = (j & 1) ? (comp >> 16) : (comp & 0xffffu);
            }
            uint4 o4;
            o4.x = e[0] | (e[1] << 16);
            o4.y = e[2] | (e[3] << 16);
            o4.z = e[4] | (e[5] << 16);
            o4.w = e[6] | (e[7] << 16);
            *(uint4*)(dstp + (size_t)(t0 + j) * R_ + r0) = o4;
        }
    }
}

// =====================================================================
// K2 (MFMA): per (t-half, c, b): Zt[t][o] = sum_r yT[t][r] * W[o][r].
// M=256(t), N=64(o), K=256(r). Wave: 64-t strip, 4x4 16x16 tiles.
// Output Z[b][o][c][t] bf16 (t-contig) via 8B packed stores.
// =====================================================================
__global__ __launch_bounds__(256) void k2_mfma(const unsigned short* __restrict__ yT,
                                               const unsigned short* __restrict__ Wb,
                                               unsigned short* __restrict__ Z) {
    const int th = blockIdx.x, c = blockIdx.y, b = blockIdx.z;
    const int tid = threadIdx.x;
    const int w = tid >> 6, l = tid & 63;
    const int lm = l & 15, lk = (l >> 4) * 8;

    const unsigned short* ab = yT + ((size_t)(b * C_ + c)) * T_ * R_;   // [t][r]
    const unsigned short* wb = Wb + (size_t)c * R_;                     // + o*C_*R_
    const int tbase = th * 256 + w * 64;

    f32x4 acc[4][4];
#pragma unroll
    for (int i = 0; i < 4; ++i)
#pragma unroll
        for (int j = 0; j < 4; ++j) acc[i][j] = (f32x4){0.f, 0.f, 0.f, 0.f};

    for (int r0 = 0; r0 < R_; r0 += 32) {
        short8 A[4], Bf[4];
#pragma unroll
        for (int mt = 0; mt < 4; ++mt)
            A[mt] = *(const short8*)(ab + (size_t)(tbase + mt * 16 + lm) * R_ + r0 + lk);
#pragma unroll
        for (int nt = 0; nt < 4; ++nt)
            Bf[nt] = *(const short8*)(wb + (size_t)(nt * 16 + lm) * (C_ * R_) + r0 + lk);
#pragma unroll
        for (int mt = 0; mt < 4; ++mt)
#pragma unroll
            for (int nt = 0; nt < 4; ++nt)
                acc[mt][nt] = __builtin_amdgcn_mfma_f32_16x16x32_bf16(A[mt], Bf[nt], acc[mt][nt], 0, 0, 0);
    }

    const int rowb = (l >> 4) * 4;
#pragma unroll
    for (int mt = 0; mt < 4; ++mt) {
#pragma unroll
        for (int nt = 0; nt < 4; ++nt) {
            const int o = nt * 16 + lm;
            const int tb = tbase + mt * 16 + rowb;
            uint2 pk;
            pk.x = (unsigned)f2bf(acc[mt][nt][0]) | ((unsigned)f2bf(acc[mt][nt][1]) << 16);
            pk.y = (unsigned)f2bf(acc[mt][nt][2]) | ((unsigned)f2bf(acc[mt][nt][3]) << 16);
            *(uint2*)(Z + (((size_t)b * C1_ + o) * C_ + c) * T_ + tb) = pk;
        }
    }
}

// =====================================================================
// K3 fused (MFMA): e[b,o,r] = leaky(sum_{c,t} y[b,c,r,t]*Z[b,o,c,t] + b_edge[o])
// Grid 512 = (16 r-tiles x 32 b), b FASTEST so the 16 blocks sharing b
// land on one XCD (blockIdx%8 == b%8) -> Z[b] (1 MB) stays L2-resident
// across its 16 re-reads. Block: 4 waves, wave w owns c in [4w,4w+4);
// per wave M=16(r), N=64(o), K=4x512(t). Cross-wave c-sum via LDS.
// Eliminates the 268 MB partial3 f32 round-trip + the k3b kernel.
// =====================================================================
__global__ __launch_bounds__(256) void k3_fused(const unsigned short* __restrict__ y,
                                                const unsigned short* __restrict__ Z,
                                                const float* __restrict__ b_edge,
                                                float* __restrict__ eT) {
    const int bid = blockIdx.x;
    const int b = bid & 31, rt = bid >> 5;
    const int r0 = rt * 16;
    const int tid = threadIdx.x;
    const int w = tid >> 6, l = tid & 63;
    const int lm = l & 15, lk = (l >> 4) * 8;

    __shared__ float red[4][C1_ * 17];   // [wave][o][r] padded stride 17 (conflict-free)

    f32x4 acc[4];
#pragma unroll
    for (int j = 0; j < 4; ++j) acc[j] = (f32x4){0.f, 0.f, 0.f, 0.f};

    const unsigned short* yb = y + (size_t)b * C_ * R_ * T_;        // + c*R*T
    const unsigned short* zb = Z + (size_t)b * C1_ * C_ * T_;       // + (o*C + c)*T

#pragma unroll
    for (int cc = 0; cc < 4; ++cc) {
        const int c = w * 4 + cc;
        const unsigned short* ya = yb + ((size_t)c * R_ + r0 + lm) * T_ + lk;
        const unsigned short* za = zb + ((size_t)(lm * C_ + c)) * T_ + lk;
#pragma unroll 4
        for (int t0 = 0; t0 < T_; t0 += 32) {
            short8 A  = *(const short8*)(ya + t0);
            short8 B0 = *(const short8*)(za + t0);
            short8 B1 = *(const short8*)(za + (size_t)16 * C_ * T_ + t0);
            short8 B2 = *(const short8*)(za + (size_t)32 * C_ * T_ + t0);
            short8 B3 = *(const short8*)(za + (size_t)48 * C_ * T_ + t0);
            acc[0] = __builtin_amdgcn_mfma_f32_16x16x32_bf16(A, B0, acc[0], 0, 0, 0);
            acc[1] = __builtin_amdgcn_mfma_f32_16x16x32_bf16(A, B1, acc[1], 0, 0, 0);
            acc[2] = __builtin_amdgcn_mfma_f32_16x16x32_bf16(A, B2, acc[2], 0, 0, 0);
            acc[3] = __builtin_amdgcn_mfma_f32_16x16x32_bf16(A, B3, acc[3], 0, 0, 0);
        }
    }

    const int rowb = (l >> 4) * 4;
#pragma unroll
    for (int nt = 0; nt < 4; ++nt) {
        const int o = nt * 16 + lm;
#pragma unroll
        for (int j = 0; j < 4; ++j)
            red[w][o * 17 + rowb + j] = acc[nt][j];
    }
    __syncthreads();

    {
        const int r = tid & 15, og = tid >> 4;   // og 0..15
#pragma unroll
        for (int k = 0; k < 4; ++k) {
            const int o = og * 4 + k;
            const int a = o * 17 + r;
            float s = red[0][a] + red[1][a] + red[2][a] + red[3][a];
            s += b_edge[o];
            s = s >= 0.f ? s : 0.01f * s;
            eT[((size_t)b * C1_ + o) * R_ + r0 + r] = s;
        }
    }
}

// =====================================================================
// K4: attention MLP (reads eT[b,o,r]). One block per b.
// W1 matvec now 4-way split over r (256 threads active, LDS reduce).
// =====================================================================
__global__ __launch_bounds__(256) void k4_att(const float* __restrict__ eT,
                                              const float* __restrict__ W1, const float* __restrict__ b1,
                                              const float* __restrict__ W2, const float* __restrict__ b2,
                                              float* __restrict__ out_att) {
    const int b = blockIdx.x, tid = threadIdx.x;
    __shared__ float pooled[R_];
    __shared__ float hp[4][64];
    __shared__ float h[64];
    {
        const float* eb = eT + (size_t)b * C1_ * R_;
        float s = 0.f;
#pragma unroll
        for (int o = 0; o < C1_; ++o) s += eb[o * R_ + tid];
        pooled[tid] = s * (1.f / 64.f);
    }
    __syncthreads();
    {
        const int i = tid & 63, q = tid >> 6;
        const float* w = W1 + i * R_ + q * 64;
        const float* p = pooled + q * 64;
        float a = 0.f;
#pragma unroll
        for (int r = 0; r < 64; ++r) a += w[r] * p[r];
        hp[q][i] = a;
    }
    __syncthreads();
    if (tid < 64)
        h[tid] = fmaxf(b1[tid] + hp[0][tid] + hp[1][tid] + hp[2][tid] + hp[3][tid], 0.f);
    __syncthreads();
    {
        float a = b2[tid];
        const float* w = W2 + tid * 64;
#pragma unroll
        for (int j = 0; j < 64; ++j) a += w[j] * h[j];
        out_att[b * R_ + tid] = 1.f / (1.f + __expf(-a));
    }
}

// =====================================================================
// K5a: K-split GEMM over k=c1*256+r; block kc owns 64-wide K-chunk.
// =====================================================================
__global__ __launch_bounds__(256) void k5_gemm(const float* __restrict__ eT,
                                               const float* __restrict__ att,
                                               const float* __restrict__ W_node,
                                               float* __restrict__ partial) {
    const int kc = blockIdx.x;          // 0..255
    const int k0 = kc * 64;
    const int r0 = k0 & 255;
    const int tid = threadIdx.x;

    __shared__ __align__(16) float gs[32 * 68];    // [b][17 float4]
    __shared__ __align__(16) float Ws[128 * 68];   // [oc][17 float4]
    float4* gs4 = reinterpret_cast<float4*>(gs);
    float4* Ws4 = reinterpret_cast<float4*>(Ws);

    {
        const int b = tid >> 3;
        const float4* ebase = reinterpret_cast<const float4*>(eT) + (size_t)b * 4096 + (k0 >> 2);
        const float4* abase = reinterpret_cast<const float4*>(att + b * R_ + r0);
#pragma unroll
        for (int j = 0; j < 2; ++j) {
            const int kk4 = (tid & 7) + j * 8;
            float4 v = ebase[kk4];
            float4 a = abase[kk4];
            v.x *= a.x; v.y *= a.y; v.z *= a.z; v.w *= a.w;
            gs4[b * 17 + kk4] = v;
        }
    }
    {
        const float4* wbase = reinterpret_cast<const float4*>(W_node) + (k0 >> 2);
#pragma unroll
        for (int j = 0; j < 8; ++j) {
            const int i = j * 256 + tid;
            const int oc = i >> 4, col4 = i & 15;
            Ws4[oc * 17 + col4] = wbase[(size_t)oc * 4096 + col4];
        }
    }
    __syncthreads();

    const int tx = tid & 31, ty = tid >> 5;
    float acc[4][4];
#pragma unroll
    for (int i = 0; i < 4; ++i)
#pragma unroll
        for (int j = 0; j < 4; ++j) acc[i][j] = 0.f;

#pragma unroll
    for (int kk4 = 0; kk4 < 16; ++kk4) {
        float4 g4[4], w4[4];
#pragma unroll
        for (int i = 0; i < 4; ++i) g4[i] = gs4[(ty + 8 * i) * 17 + kk4];
#pragma unroll
        for (int j = 0; j < 4; ++j) w4[j] = Ws4[(tx + 32 * j) * 17 + kk4];
#pragma unroll
        for (int i = 0; i < 4; ++i)
#pragma unroll
            for (int j = 0; j < 4; ++j)
                acc[i][j] += g4[i].x * w4[j].x + g4[i].y * w4[j].y
                           + g4[i].z * w4[j].z + g4[i].w * w4[j].w;
    }

    float* d = partial + (size_t)kc * (B_ * C2_);
#pragma unroll
    for (int i = 0; i < 4; ++i)
#pragma unroll
        for (int j = 0; j < 4; ++j)
            d[(ty + 8 * i) * C2_ + tx + 32 * j] = acc[i][j];
}

// K5b: out[b,oc] = leaky(sum_kc partial[kc][b][oc] + b_node[oc])
__global__ __launch_bounds__(256) void k5_reduce(const float* __restrict__ partial,
                                                 const float* __restrict__ b_node,
                                                 float* __restrict__ out_o) {
    const int idx = blockIdx.x * 256 + threadIdx.x;   // < 4096
    float s = 0.f;
    for (int kc = 0; kc < 256; ++kc) s += partial[(size_t)kc * (B_ * C2_) + idx];
    s += b_node[idx & 127];
    out_o[idx] = s >= 0.f ? s : 0.01f * s;
}

extern "C" void kernel_launch(void* const* d_in, const int* in_sizes, int n_in,
                              void* d_out, int out_size, void* d_ws, size_t ws_size,
                              hipStream_t stream) {
    const float* x      = (const float*)d_in[0];
    const float* W_edge = (const float*)d_in[1];
    const float* b_edge = (const float*)d_in[2];
    const float* W1     = (const float*)d_in[3];
    const float* b1     = (const float*)d_in[4];
    const float* W2     = (const float*)d_in[5];
    const float* b2     = (const float*)d_in[6];
    const float* W_node = (const float*)d_in[7];
    const float* b_node = (const float*)d_in[8];
    float* out = (float*)d_out;   // [0,4096): o ; [4096,12288): att

    char* ws = (char*)d_ws;
    unsigned short* y  = (unsigned short*)ws;                 // 134217728 B [B,C,R,T] bf16
    unsigned short* yT = (unsigned short*)(ws + 134217728);   // 134217728 B [B,C,T,R] bf16
    unsigned short* Z  = (unsigned short*)(ws + 268435456);   //  33554432 B [B,C1,C,T] bf16
    unsigned short* Wb = (unsigned short*)(ws + 301989888);   //    524288 B [C1,C,R] bf16
    float* eT          = (float*)(ws + 302514176);            //   2097152 B [B,C1,R] f32
    float* partial5    = (float*)(ws + 304611328);            //   4194304 B [256,B,C2] f32

    k0_wcvt<<<256, 256, 0, stream>>>(W_edge, Wb);
    k1_normalize<<<dim3(R_, B_), 256, 0, stream>>>(x, y);
    k1t_transpose<<<dim3(C_, B_), 256, 0, stream>>>(y, yT);
    k2_mfma<<<dim3(2, C_, B_), 256, 0, stream>>>(yT, Wb, Z);
    k3_fused<<<512, 256, 0, stream>>>(y, Z, b_edge, eT);
    k4_att<<<B_, 256, 0, stream>>>(eT, W1, b1, W2, b2, out + 4096);
    k5_gemm<<<256, 256, 0, stream>>>(eT, out + 4096, W_node, partial5);
    k5_reduce<<<16, 256, 0, stream>>>(partial5, b_node, out);
}

// Round 2
// 504.259 us; speedup vs baseline: 1.1854x; 1.1854x over previous
//
#include <hip/hip_runtime.h>
#include <hip/hip_bf16.h>

#define B_  32
#define R_  256
#define T_  512
#define C_  16
#define C1_ 64
#define C2_ 128

typedef short short8 __attribute__((ext_vector_type(8)));   // 8 bf16 = 4 VGPRs (MFMA A/B frag)
typedef float f32x4  __attribute__((ext_vector_type(4)));   // MFMA C/D frag

// ---------- bf16 helpers (RNE rounding) ----------
__device__ __forceinline__ unsigned short f2bf(float f) {
    unsigned u = __float_as_uint(f);
    return (unsigned short)((u + 0x7fffu + ((u >> 16) & 1u)) >> 16);
}

// =====================================================================
// K0: W_edge fp32 [o][c][r] -> Wb bf16 (same flat order), one-time cvt.
// =====================================================================
__global__ __launch_bounds__(256) void k0_wcvt(const float* __restrict__ W,
                                               unsigned short* __restrict__ Wb) {
    const int i = (blockIdx.x * 256 + threadIdx.x) * 4;   // 262144 total
    float4 v = *(const float4*)(W + i);
    uint2 pk;
    pk.x = (unsigned)f2bf(v.x) | ((unsigned)f2bf(v.y) << 16);
    pk.y = (unsigned)f2bf(v.z) | ((unsigned)f2bf(v.w) << 16);
    *(uint2*)(Wb + i) = pk;
}

// =====================================================================
// K1: x[B,R,T,C] fp32 -> y[B,C,R,T] bf16, rows centered & L2-normalized.
// =====================================================================
__global__ __launch_bounds__(256) void k1_normalize(const float* __restrict__ x,
                                                    unsigned short* __restrict__ y) {
    const int r = blockIdx.x, b = blockIdx.y, tid = threadIdx.x;
    __shared__ float xs[T_ * C_];          // 32 KB
    __shared__ float psum[16][17], psq[16][17];
    __shared__ float s_mean[16], s_inv[16];

    const float4* src = reinterpret_cast<const float4*>(x + ((size_t)(b * R_ + r)) * T_ * C_);
    float4* dst = reinterpret_cast<float4*>(xs);
#pragma unroll
    for (int j = 0; j < 8; ++j) dst[tid + j * 256] = src[tid + j * 256];
    __syncthreads();

    {
        const int c = tid & 15, seg = tid >> 4;
        float s = 0.f, q = 0.f;
#pragma unroll
        for (int i = 0; i < 32; ++i) {
            float v = xs[(seg * 32 + i) * C_ + c];
            s += v; q += v * v;
        }
        psum[seg][c] = s; psq[seg][c] = q;
    }
    __syncthreads();
    if (tid < 16) {
        float S = 0.f, Q = 0.f;
#pragma unroll
        for (int g = 0; g < 16; ++g) { S += psum[g][tid]; Q += psq[g][tid]; }
        float mean = S * (1.f / T_);
        float nrm2 = Q - S * mean;
        s_mean[tid] = mean;
        s_inv[tid] = rsqrtf(nrm2);
    }
    __syncthreads();

    const int cc = tid >> 4, l = tid & 15;
    const float mean = s_mean[cc], inv = s_inv[cc];
    unsigned* out = reinterpret_cast<unsigned*>(y + (((size_t)(b * C_ + cc)) * R_ + r) * T_);
#pragma unroll
    for (int j = 0; j < 16; ++j) {
        const int t = j * 32 + l * 2;
        float v0 = (xs[t * C_ + cc] - mean) * inv;
        float v1 = (xs[(t + 1) * C_ + cc] - mean) * inv;
        out[t >> 1] = (unsigned)f2bf(v0) | ((unsigned)f2bf(v1) << 16);
    }
}

// =====================================================================
// K2 (MFMA, in-kernel transpose): per (t-half, c, b):
//   Zt[t][o] = sum_r y[b,c,r,t] * W[o][c][r]
// M=256(t), N=64(o), K=256(r) in 8 steps of 32.
// Staging: wave-coalesced 8B loads of y (t-contig), register repack
// (k1t pattern), LDS tile [256 t][32 r] with 40-elem (80 B) padded
// row stride -> b128 writes AND reads conflict-free & 16B-aligned.
// Double-buffered, 1 barrier/step. Replaces the 268 MB yT round-trip.
// =====================================================================
__global__ __launch_bounds__(256) void k2_mfma(const unsigned short* __restrict__ y,
                                               const unsigned short* __restrict__ Wb,
                                               unsigned short* __restrict__ Z) {
    const int th = blockIdx.x, c = blockIdx.y, b = blockIdx.z;
    const int tid = threadIdx.x;
    const int w = tid >> 6, l = tid & 63;
    const int lm = l & 15, lk = (l >> 4) * 8;

    __shared__ __align__(16) unsigned short ldsT[2][256 * 40];   // 40960 B

    const unsigned short* yb = y + ((size_t)(b * C_ + c)) * R_ * T_;   // [r][t]
    const unsigned short* wb = Wb + (size_t)c * R_;                    // + o*C_*R_
    const int tb0 = th * 256;

    // staging mapping: wave = r-oct, lane = t-quad
    const int st_t0 = (tid & 63) * 4;      // local t 0..252
    const int st_r0 = (tid >> 6) * 8;      // local r 0..24

    f32x4 acc[4][4];
#pragma unroll
    for (int i = 0; i < 4; ++i)
#pragma unroll
        for (int j = 0; j < 4; ++j) acc[i][j] = (f32x4){0.f, 0.f, 0.f, 0.f};

    // ---- stage step 0 ----
    {
        const unsigned short* src = yb + (size_t)st_r0 * T_ + tb0 + st_t0;
        uint2 u[8];
#pragma unroll
        for (int k = 0; k < 8; ++k) u[k] = *(const uint2*)(src + (size_t)k * T_);
#pragma unroll
        for (int j = 0; j < 4; ++j) {
            unsigned e[8];
#pragma unroll
            for (int k = 0; k < 8; ++k) {
                unsigned comp = (j < 2) ? u[k].x : u[k].y;
                e[k] = (j & 1) ? (comp >> 16) : (comp & 0xffffu);
            }
            uint4 o4;
            o4.x = e[0] | (e[1] << 16);
            o4.y = e[2] | (e[3] << 16);
            o4.z = e[4] | (e[5] << 16);
            o4.w = e[6] | (e[7] << 16);
            *(uint4*)&ldsT[0][(st_t0 + j) * 40 + st_r0] = o4;
        }
    }
    __syncthreads();

    for (int s = 0; s < 8; ++s) {
        const int r0 = s * 32;
        // issue next-step global loads early (hide under MFMA)
        uint2 u[8];
        if (s < 7) {
            const unsigned short* src = yb + (size_t)(r0 + 32 + st_r0) * T_ + tb0 + st_t0;
#pragma unroll
            for (int k = 0; k < 8; ++k) u[k] = *(const uint2*)(src + (size_t)k * T_);
        }

        // compute step s from ldsT[s&1]
        const unsigned short* base = &ldsT[s & 1][0];
        short8 A[4], Bf[4];
#pragma unroll
        for (int mt = 0; mt < 4; ++mt)
            A[mt] = *(const short8*)(base + (w * 64 + mt * 16 + lm) * 40 + lk);
#pragma unroll
        for (int nt = 0; nt < 4; ++nt)
            Bf[nt] = *(const short8*)(wb + (size_t)(nt * 16 + lm) * (C_ * R_) + r0 + lk);
#pragma unroll
        for (int mt = 0; mt < 4; ++mt)
#pragma unroll
            for (int nt = 0; nt < 4; ++nt)
                acc[mt][nt] = __builtin_amdgcn_mfma_f32_16x16x32_bf16(A[mt], Bf[nt], acc[mt][nt], 0, 0, 0);

        // repack + write next tile
        if (s < 7) {
            unsigned short* nbuf = &ldsT[(s + 1) & 1][0];
#pragma unroll
            for (int j = 0; j < 4; ++j) {
                unsigned e[8];
#pragma unroll
                for (int k = 0; k < 8; ++k) {
                    unsigned comp = (j < 2) ? u[k].x : u[k].y;
                    e[k] = (j & 1) ? (comp >> 16) : (comp & 0xffffu);
                }
                uint4 o4;
                o4.x = e[0] | (e[1] << 16);
                o4.y = e[2] | (e[3] << 16);
                o4.z = e[4] | (e[5] << 16);
                o4.w = e[6] | (e[7] << 16);
                *(uint4*)&nbuf[(st_t0 + j) * 40 + st_r0] = o4;
            }
        }
        __syncthreads();
    }

    const int rowb = (l >> 4) * 4;
    const int tbase = tb0 + w * 64;
#pragma unroll
    for (int mt = 0; mt < 4; ++mt) {
#pragma unroll
        for (int nt = 0; nt < 4; ++nt) {
            const int o = nt * 16 + lm;
            const int tb = tbase + mt * 16 + rowb;
            uint2 pk;
            pk.x = (unsigned)f2bf(acc[mt][nt][0]) | ((unsigned)f2bf(acc[mt][nt][1]) << 16);
            pk.y = (unsigned)f2bf(acc[mt][nt][2]) | ((unsigned)f2bf(acc[mt][nt][3]) << 16);
            *(uint2*)(Z + (((size_t)b * C1_ + o) * C_ + c) * T_ + tb) = pk;
        }
    }
}

// =====================================================================
// K3 (MFMA): per (c, b): partial[c][b][o][r] = sum_t y[b,c,r,t]*Z[b,o,c,t]
// M=256(r), N=64(o), K=512(t). Wave: 64-r strip, 4x4 16x16 tiles.
// Both frags t-contiguous -> direct 16B global loads, no LDS.
// =====================================================================
__global__ __launch_bounds__(256) void k3_mfma(const unsigned short* __restrict__ y,
                                               const unsigned short* __restrict__ Z,
                                               float* __restrict__ partial) {
    const int c = blockIdx.x, b = blockIdx.y;
    const int tid = threadIdx.x;
    const int w = tid >> 6, l = tid & 63;
    const int lm = l & 15, lk = (l >> 4) * 8;

    const unsigned short* yb = y + ((size_t)(b * C_ + c)) * R_ * T_;        // [r][t]
    const unsigned short* zb = Z + ((size_t)b * C1_ * C_ + c) * T_;         // + o*C_*T_

    f32x4 acc[4][4];
#pragma unroll
    for (int i = 0; i < 4; ++i)
#pragma unroll
        for (int j = 0; j < 4; ++j) acc[i][j] = (f32x4){0.f, 0.f, 0.f, 0.f};

    for (int t0 = 0; t0 < T_; t0 += 32) {
        short8 A[4], Bf[4];
#pragma unroll
        for (int mt = 0; mt < 4; ++mt)
            A[mt] = *(const short8*)(yb + (size_t)(w * 64 + mt * 16 + lm) * T_ + t0 + lk);
#pragma unroll
        for (int nt = 0; nt < 4; ++nt)
            Bf[nt] = *(const short8*)(zb + (size_t)(nt * 16 + lm) * (C_ * T_) + t0 + lk);
#pragma unroll
        for (int mt = 0; mt < 4; ++mt)
#pragma unroll
            for (int nt = 0; nt < 4; ++nt)
                acc[mt][nt] = __builtin_amdgcn_mfma_f32_16x16x32_bf16(A[mt], Bf[nt], acc[mt][nt], 0, 0, 0);
    }

    const int rowb = (l >> 4) * 4;
#pragma unroll
    for (int mt = 0; mt < 4; ++mt) {
#pragma unroll
        for (int nt = 0; nt < 4; ++nt) {
            const int o = nt * 16 + lm;
            const int rb = w * 64 + mt * 16 + rowb;
            float* d = partial + (((size_t)c * B_ + b) * C1_ + o) * R_ + rb;
            *(float4*)d = make_float4(acc[mt][nt][0], acc[mt][nt][1], acc[mt][nt][2], acc[mt][nt][3]);
        }
    }
}

// K3b: eT[b,o,r] = leaky_relu(sum_c partial[c][b][o][r] + b_edge[o])
__global__ __launch_bounds__(256) void k3b_combine(const float* __restrict__ partial,
                                                   const float* __restrict__ b_edge,
                                                   float* __restrict__ eT) {
    const int idx4 = blockIdx.x * 256 + threadIdx.x;   // 0..131071 (float4 index)
    const float4* p = (const float4*)partial;
    float4 s = p[idx4];
#pragma unroll
    for (int c = 1; c < C_; ++c) {
        float4 v = p[(size_t)c * 131072 + idx4];
        s.x += v.x; s.y += v.y; s.z += v.z; s.w += v.w;
    }
    const float bo = b_edge[(idx4 >> 6) & 63];
    s.x += bo; s.y += bo; s.z += bo; s.w += bo;
    s.x = s.x >= 0.f ? s.x : 0.01f * s.x;
    s.y = s.y >= 0.f ? s.y : 0.01f * s.y;
    s.z = s.z >= 0.f ? s.z : 0.01f * s.z;
    s.w = s.w >= 0.f ? s.w : 0.01f * s.w;
    ((float4*)eT)[idx4] = s;
}

// =====================================================================
// K4: attention MLP (reads eT[b,o,r]). One block per b.
// W1 matvec 4-way split over r (256 threads active, LDS reduce).
// =====================================================================
__global__ __launch_bounds__(256) void k4_att(const float* __restrict__ eT,
                                              const float* __restrict__ W1, const float* __restrict__ b1,
                                              const float* __restrict__ W2, const float* __restrict__ b2,
                                              float* __restrict__ out_att) {
    const int b = blockIdx.x, tid = threadIdx.x;
    __shared__ float pooled[R_];
    __shared__ float hp[4][64];
    __shared__ float h[64];
    {
        const float* eb = eT + (size_t)b * C1_ * R_;
        float s = 0.f;
#pragma unroll
        for (int o = 0; o < C1_; ++o) s += eb[o * R_ + tid];
        pooled[tid] = s * (1.f / 64.f);
    }
    __syncthreads();
    {
        const int i = tid & 63, q = tid >> 6;
        const float* w = W1 + i * R_ + q * 64;
        const float* p = pooled + q * 64;
        float a = 0.f;
#pragma unroll
        for (int r = 0; r < 64; ++r) a += w[r] * p[r];
        hp[q][i] = a;
    }
    __syncthreads();
    if (tid < 64)
        h[tid] = fmaxf(b1[tid] + hp[0][tid] + hp[1][tid] + hp[2][tid] + hp[3][tid], 0.f);
    __syncthreads();
    {
        float a = b2[tid];
        const float* w = W2 + tid * 64;
#pragma unroll
        for (int j = 0; j < 64; ++j) a += w[j] * h[j];
        out_att[b * R_ + tid] = 1.f / (1.f + __expf(-a));
    }
}

// =====================================================================
// K5a: K-split GEMM over k=c1*256+r; block kc owns 64-wide K-chunk.
// =====================================================================
__global__ __launch_bounds__(256) void k5_gemm(const float* __restrict__ eT,
                                               const float* __restrict__ att,
                                               const float* __restrict__ W_node,
                                               float* __restrict__ partial) {
    const int kc = blockIdx.x;          // 0..255
    const int k0 = kc * 64;
    const int r0 = k0 & 255;
    const int tid = threadIdx.x;

    __shared__ __align__(16) float gs[32 * 68];    // [b][17 float4]
    __shared__ __align__(16) float Ws[128 * 68];   // [oc][17 float4]
    float4* gs4 = reinterpret_cast<float4*>(gs);
    float4* Ws4 = reinterpret_cast<float4*>(Ws);

    {
        const int b = tid >> 3;
        const float4* ebase = reinterpret_cast<const float4*>(eT) + (size_t)b * 4096 + (k0 >> 2);
        const float4* abase = reinterpret_cast<const float4*>(att + b * R_ + r0);
#pragma unroll
        for (int j = 0; j < 2; ++j) {
            const int kk4 = (tid & 7) + j * 8;
            float4 v = ebase[kk4];
            float4 a = abase[kk4];
            v.x *= a.x; v.y *= a.y; v.z *= a.z; v.w *= a.w;
            gs4[b * 17 + kk4] = v;
        }
    }
    {
        const float4* wbase = reinterpret_cast<const float4*>(W_node) + (k0 >> 2);
#pragma unroll
        for (int j = 0; j < 8; ++j) {
            const int i = j * 256 + tid;
            const int oc = i >> 4, col4 = i & 15;
            Ws4[oc * 17 + col4] = wbase[(size_t)oc * 4096 + col4];
        }
    }
    __syncthreads();

    const int tx = tid & 31, ty = tid >> 5;
    float acc[4][4];
#pragma unroll
    for (int i = 0; i < 4; ++i)
#pragma unroll
        for (int j = 0; j < 4; ++j) acc[i][j] = 0.f;

#pragma unroll
    for (int kk4 = 0; kk4 < 16; ++kk4) {
        float4 g4[4], w4[4];
#pragma unroll
        for (int i = 0; i < 4; ++i) g4[i] = gs4[(ty + 8 * i) * 17 + kk4];
#pragma unroll
        for (int j = 0; j < 4; ++j) w4[j] = Ws4[(tx + 32 * j) * 17 + kk4];
#pragma unroll
        for (int i = 0; i < 4; ++i)
#pragma unroll
            for (int j = 0; j < 4; ++j)
                acc[i][j] += g4[i].x * w4[j].x + g4[i].y * w4[j].y
                           + g4[i].z * w4[j].z + g4[i].w * w4[j].w;
    }

    float* d = partial + (size_t)kc * (B_ * C2_);
#pragma unroll
    for (int i = 0; i < 4; ++i)
#pragma unroll
        for (int j = 0; j < 4; ++j)
            d[(ty + 8 * i) * C2_ + tx + 32 * j] = acc[i][j];
}

// K5b: out[b,oc] = leaky(sum_kc partial[kc][b][oc] + b_node[oc])
__global__ __launch_bounds__(256) void k5_reduce(const float* __restrict__ partial,
                                                 const float* __restrict__ b_node,
                                                 float* __restrict__ out_o) {
    const int idx = blockIdx.x * 256 + threadIdx.x;   // < 4096
    float s = 0.f;
    for (int kc = 0; kc < 256; ++kc) s += partial[(size_t)kc * (B_ * C2_) + idx];
    s += b_node[idx & 127];
    out_o[idx] = s >= 0.f ? s : 0.01f * s;
}

extern "C" void kernel_launch(void* const* d_in, const int* in_sizes, int n_in,
                              void* d_out, int out_size, void* d_ws, size_t ws_size,
                              hipStream_t stream) {
    const float* x      = (const float*)d_in[0];
    const float* W_edge = (const float*)d_in[1];
    const float* b_edge = (const float*)d_in[2];
    const float* W1     = (const float*)d_in[3];
    const float* b1     = (const float*)d_in[4];
    const float* W2     = (const float*)d_in[5];
    const float* b2     = (const float*)d_in[6];
    const float* W_node = (const float*)d_in[7];
    const float* b_node = (const float*)d_in[8];
    float* out = (float*)d_out;   // [0,4096): o ; [4096,12288): att

    char* ws = (char*)d_ws;
    unsigned short* y  = (unsigned short*)ws;                 // 134217728 B [B,C,R,T] bf16
    unsigned short* Z  = (unsigned short*)(ws + 134217728);   //  33554432 B [B,C1,C,T] bf16
    unsigned short* Wb = (unsigned short*)(ws + 167772160);   //    524288 B [C1,C,R] bf16
    float* partial3    = (float*)(ws + 168296448);            //  33554432 B [C][B][C1][R] f32
    float* eT          = (float*)(ws + 201850880);            //   2097152 B [B,C1,R] f32
    float* partial5    = (float*)(ws + 203948032);            //   4194304 B [256,B,C2] f32

    k0_wcvt<<<256, 256, 0, stream>>>(W_edge, Wb);
    k1_normalize<<<dim3(R_, B_), 256, 0, stream>>>(x, y);
    k2_mfma<<<dim3(2, C_, B_), 256, 0, stream>>>(y, Wb, Z);
    k3_mfma<<<dim3(C_, B_), 256, 0, stream>>>(y, Z, partial3);
    k3b_combine<<<512, 256, 0, stream>>>(partial3, b_edge, eT);
    k4_att<<<B_, 256, 0, stream>>>(eT, W1, b1, W2, b2, out + 4096);
    k5_gemm<<<256, 256, 0, stream>>>(eT, out + 4096, W_node, partial5);
    k5_reduce<<<16, 256, 0, stream>>>(partial5, b_node, out);
}